// Round 2
// baseline (13442.213 us; speedup 1.0000x reference)
//
// Decoder_56530359550871 — round 3: persistent cooperative recurrence
//  * whole 64-step recurrence in ONE hipLaunchCooperativeKernel (256 blocks x 512),
//    4 phases/step separated by grid.sync():
//      P1 gates0+cell (256 blk) | P2 gates1+cell (256 blk)
//      P3 attention (blk 0..127: scores in LDS + softmax + summary) ||
//         cpart = h1'@Wc[:,:H]^T (blk 128..191)
//      P4 comb = cpart + summ@Wc[:,H:]^T + bc (blk 0..63)
//    -> kills ~320 dependent kernel launches (~11 us each).
//  * scores buffer now LDS-resident (scoresbuf round-trip removed).
//  * numerics identical to round 2 (same MFMA tiling, same reduce order).
//  * fallback: if cooperative launch fails, same device code as 4 launches/step.
// Phase A and Phase C unchanged from round 2.

#include <hip/hip_runtime.h>
#include <hip/hip_cooperative_groups.h>
#include <stdint.h>
#include <math.h>

namespace cg = cooperative_groups;

#define Td 64
#define Bd 64
#define Sd 256
#define Ed 512
#define Hd 1024
#define Vd 16000
#define G4 4096

typedef short v8s __attribute__((ext_vector_type(8)));
typedef float v4f __attribute__((ext_vector_type(4)));

__device__ __forceinline__ float b2f(unsigned short v) {
  union { unsigned int u; float f; } x; x.u = ((unsigned int)v) << 16; return x.f;
}
__device__ __forceinline__ unsigned short f2b(float f) {
  union { float f; unsigned int u; } x; x.f = f;
  unsigned int u = x.u + 0x7fffu + ((x.u >> 16) & 1u);
  return (unsigned short)(u >> 16);
}

// ---------------- Phase A kernels ----------------

__global__ __launch_bounds__(256) void k_f2b(const float* __restrict__ s,
                                             unsigned short* __restrict__ d, int n) {
  int i = blockIdx.x * 256 + threadIdx.x;
  if (i < n) d[i] = f2b(s[i]);
}

__global__ __launch_bounds__(256) void k_cvtgate(const float* __restrict__ ih,
                                                 const float* __restrict__ hh,
                                                 unsigned short* __restrict__ dst,
                                                 int Kih, int Ktot) {
  int i = blockIdx.x * 256 + threadIdx.x;
  int np = i / Ktot;
  int k = i - np * Ktot;
  int n = ((np & 3) << 10) + (np >> 2);
  float v = (k < Kih) ? ih[(size_t)n * Kih + k]
                      : hh[(size_t)n * (Ktot - Kih) + (k - Kih)];
  dst[i] = f2b(v);
}

__global__ __launch_bounds__(256) void k_embed(const int* __restrict__ tok,
                                               const float* __restrict__ ew,
                                               unsigned short* __restrict__ dst) {
  int i = blockIdx.x * 256 + threadIdx.x;  // T*B*E
  int e = i & (Ed - 1);
  int tb = i >> 9;
  dst[i] = f2b(ew[(size_t)tok[tb] * Ed + e]);
}

// MTT[k][n] = sum_j Wk[j,n] * Wq[j,k]
__global__ __launch_bounds__(256) void k_mt(const float* __restrict__ Wk,
                                            const float* __restrict__ Wq,
                                            unsigned short* __restrict__ MTT) {
  __shared__ float sk[32][33], sq[32][33];
  int tx = threadIdx.x & 15, ty = threadIdx.x >> 4;
  int n0 = blockIdx.x * 32, k0 = blockIdx.y * 32;
  float a00 = 0, a01 = 0, a10 = 0, a11 = 0;
  for (int jc = 0; jc < 32; jc++) {
    __syncthreads();
    for (int i = threadIdx.x; i < 1024; i += 256) {
      int r = i >> 5, c = i & 31;
      sk[r][c] = Wk[(jc * 32 + r) * Hd + n0 + c];
      sq[r][c] = Wq[(jc * 32 + r) * Hd + k0 + c];
    }
    __syncthreads();
    for (int j = 0; j < 32; j++) {
      float kv0 = sk[j][tx], kv1 = sk[j][tx + 16];
      float qv0 = sq[j][ty], qv1 = sq[j][ty + 16];
      a00 += kv0 * qv0; a01 += kv0 * qv1; a10 += kv1 * qv0; a11 += kv1 * qv1;
    }
  }
  MTT[(k0 + ty) * Hd + n0 + tx]             = f2b(a00);
  MTT[(k0 + ty + 16) * Hd + n0 + tx]        = f2b(a01);
  MTT[(k0 + ty) * Hd + n0 + tx + 16]        = f2b(a10);
  MTT[(k0 + ty + 16) * Hd + n0 + tx + 16]   = f2b(a11);
}

__global__ __launch_bounds__(256) void k_biasq(const float* __restrict__ bq,
                                               const float* __restrict__ Wk,
                                               float* __restrict__ biasq) {
  int n = blockIdx.x * 256 + threadIdx.x;
  float a = 0;
  for (int j = 0; j < 1024; j++) a += bq[j] * Wk[j * Hd + n];
  biasq[n] = a;
}

__global__ __launch_bounds__(256) void k_sb0(const unsigned short* __restrict__ Ab,
                                             const float* __restrict__ biasq,
                                             const int* __restrict__ atok,
                                             float* __restrict__ sb0) {
  int w = blockIdx.x * 4 + (threadIdx.x >> 6);
  int lane = threadIdx.x & 63;
  int s = w >> 6, b = w & 63;
  const unsigned short* ap = Ab + ((size_t)(s * 64 + b) << 10) + lane * 16;
  v8s a0 = *(const v8s*)ap, a1 = *(const v8s*)(ap + 8);
  float acc = 0;
#pragma unroll
  for (int j = 0; j < 8; j++) {
    acc += b2f((unsigned short)a0[j]) * biasq[lane * 16 + j];
    acc += b2f((unsigned short)a1[j]) * biasq[lane * 16 + 8 + j];
  }
  for (int off = 32; off; off >>= 1) acc += __shfl_xor(acc, off, 64);
  if (lane == 0) {
    if (atok[s * 64 + b] == 0) acc += -1e9f;
    sb0[s * 64 + b] = acc;
  }
}

__global__ __launch_bounds__(256) void k_bsum(const float* __restrict__ bih,
                                              const float* __restrict__ bhh,
                                              float* __restrict__ dst) {
  int i = blockIdx.x * 256 + threadIdx.x;
  int n = ((i & 3) << 10) + (i >> 2);
  dst[i] = bih[n] + bhh[n];
}

__global__ __launch_bounds__(256) void k_init(const float* __restrict__ h0in,
                                              const float* __restrict__ c0in,
                                              unsigned short* __restrict__ h0b,
                                              unsigned short* __restrict__ h1b,
                                              float* __restrict__ c0f, float* __restrict__ c1f,
                                              unsigned short* __restrict__ feed0) {
  int i = blockIdx.x * 256 + threadIdx.x;  // B*H
  h0b[i] = f2b(h0in[i]);
  h1b[i] = f2b(h0in[Bd * Hd + i]);
  c0f[i] = c0in[i];
  c1f[i] = c0in[Bd * Hd + i];
  feed0[i] = 0;
}

// ---------------- recurrence: persistent kernel plumbing ----------------

struct PK {
  const unsigned short* embb;   // [T][64][512]
  const unsigned short* Wl0;    // [4096][2560] gate-interleaved
  const unsigned short* Wl1;    // [4096][2048] gate-interleaved
  const unsigned short* Wcb;    // [1024][2048]
  const unsigned short* AMT;    // [S*B][1024]
  const unsigned short* Aatt;   // [S][B][1024]
  const float* sb0;             // [S][B]
  const float* bsum0;           // [4096]
  const float* bsum1;           // [4096]
  const float* bc;              // [1024]
  float* c0; float* c1;         // [64][1024]
  unsigned short* h0[2];        // double buffers [64][1024]
  unsigned short* h1[2];
  const unsigned short* feed0;  // zeros
  unsigned short* combb;        // [T][64][1024]
  float* distT;                 // [T*64][256]
  unsigned short* summb;        // [64][1024]
  float* cpart;                 // [64][1024] fp32
};

// skinny GEMM (M=64, N-tile=16, 8-wave K-split, LDS reduce) + epilogue
// mode 0: LSTM cell ; mode 2: fp32 store to cpart ; mode 3: +cpart+bc -> bf16
__device__ __forceinline__ void gemm_phase(
    int tid, int n0,
    const unsigned short* a0, int l0,
    const unsigned short* a1, int l1,
    const unsigned short* a2, int l2,
    const unsigned short* W, int ldw, int cpw,
    const float* bsum, float* cst, unsigned short* hout,
    float* cpart, const float* bc, int mode,
    float (*red)[64][17]) {
  int w = tid >> 6, lane = tid & 63, lq = lane >> 4, l16 = lane & 15;
  int c0 = w * cpw;

  v4f acc[4];
#pragma unroll
  for (int mi = 0; mi < 4; mi++) acc[mi] = 0;

  auto ldA = [&](int ci, v8s af[4]) {
    int kv = (c0 + ci) * 32;
    const unsigned short* ap; int ld, ko;
    if (kv < l0) { ap = a0; ld = l0; ko = kv; }
    else if (kv < l0 + l1) { ap = a1; ld = l1; ko = kv - l0; }
    else { ap = a2; ld = l2; ko = kv - l0 - l1; }
    const unsigned short* base = ap + ko + lq * 8 + l16 * ld;
#pragma unroll
    for (int mi = 0; mi < 4; mi++) af[mi] = *(const v8s*)(base + mi * 16 * ld);
  };
  auto ldB = [&](int ci, v8s& bf) {
    bf = *(const v8s*)(W + (size_t)(n0 + l16) * ldw + (c0 + ci) * 32 + lq * 8);
  };

  v8s afc[4], afn[4], bfc, bfn;
  ldA(0, afc); ldB(0, bfc);
  for (int ci = 0; ci < cpw; ci++) {
    if (ci + 1 < cpw) { ldA(ci + 1, afn); ldB(ci + 1, bfn); }
#pragma unroll
    for (int mi = 0; mi < 4; mi++)
      acc[mi] = __builtin_amdgcn_mfma_f32_16x16x32_bf16(afc[mi], bfc, acc[mi], 0, 0, 0);
#pragma unroll
    for (int i = 0; i < 4; i++) afc[i] = afn[i];
    bfc = bfn;
  }

#pragma unroll
  for (int mi = 0; mi < 4; mi++)
#pragma unroll
    for (int r = 0; r < 4; r++)
      red[w][mi * 16 + lq * 4 + r][l16] = acc[mi][r];
  __syncthreads();

  if (mode == 0) {
    if (tid < 256) {
      int b = tid & 63, hl = tid >> 6;  // hl in 0..3
      float gv[4];
#pragma unroll
      for (int gg = 0; gg < 4; gg++) {
        float s = bsum[n0 + hl * 4 + gg];
#pragma unroll
        for (int w8 = 0; w8 < 8; w8++) s += red[w8][b][hl * 4 + gg];
        gv[gg] = s;
      }
      float si = 1.f / (1.f + expf(-gv[0]));
      float sf = 1.f / (1.f + expf(-gv[1]));
      float so = 1.f / (1.f + expf(-gv[3]));
      int h = (n0 >> 2) + hl;
      int idx = (b << 10) + h;
      float cn = sf * cst[idx] + si * tanhf(gv[2]);
      cst[idx] = cn;
      hout[idx] = f2b(so * tanhf(cn));
    }
  } else if (mode == 2) {
    int b = tid & 63, nh = tid >> 6;  // 0..7
#pragma unroll
    for (int r = 0; r < 2; r++) {
      int nl = nh * 2 + r;
      float s = 0;
#pragma unroll
      for (int w8 = 0; w8 < 8; w8++) s += red[w8][b][nl];
      cpart[(b << 10) + n0 + nl] = s;
    }
  } else {  // mode 3
    int b = tid & 63, nh = tid >> 6;
#pragma unroll
    for (int r = 0; r < 2; r++) {
      int nl = nh * 2 + r;
      float s = cpart[(b << 10) + n0 + nl] + bc[n0 + nl];
#pragma unroll
      for (int w8 = 0; w8 < 8; w8++) s += red[w8][b][nl];
      hout[(b << 10) + n0 + nl] = f2b(s);
    }
  }
}

// attention for one b: scores (LDS) -> softmax -> half of summary
__device__ __forceinline__ void att_phase(
    int tid, int b, int half, int t, const PK& g, const unsigned short* h1n,
    float* sc, float* ds) {
  int w = tid >> 6, lane = tid & 63;
  const unsigned short* qp = h1n + (b << 10) + lane * 16;
  v8s q0 = *(const v8s*)qp, q1 = *(const v8s*)(qp + 8);
  for (int si = 0; si < 32; si++) {
    int s = (w << 5) + si;
    const unsigned short* ap = g.AMT + ((size_t)((s << 6) + b) << 10) + lane * 16;
    v8s a0 = *(const v8s*)ap, a1 = *(const v8s*)(ap + 8);
    float acc = 0;
#pragma unroll
    for (int j = 0; j < 8; j++) {
      acc += b2f((unsigned short)a0[j]) * b2f((unsigned short)q0[j]);
      acc += b2f((unsigned short)a1[j]) * b2f((unsigned short)q1[j]);
    }
    for (int off = 32; off; off >>= 1) acc += __shfl_xor(acc, off, 64);
    if (lane == 0) sc[s] = acc + g.sb0[(s << 6) + b];
  }
  __syncthreads();
  float x = (tid < 256) ? sc[tid] : -3e38f;
  if (tid < 256) ds[tid] = x;
  __syncthreads();
  for (int off = 128; off; off >>= 1) {
    if (tid < off) ds[tid] = fmaxf(ds[tid], ds[tid + off]);
    __syncthreads();
  }
  float m = ds[0];
  __syncthreads();
  float e = (tid < 256) ? expf(x - m) : 0.f;
  if (tid < 256) { sc[tid] = e; ds[tid] = e; }
  __syncthreads();
  for (int off = 128; off; off >>= 1) {
    if (tid < off) ds[tid] += ds[tid + off];
    __syncthreads();
  }
  float inv = 1.f / ds[0];
  __syncthreads();
  if (tid < 256) {
    float d = sc[tid] * inv;
    sc[tid] = d;
    if (half == 0) g.distT[((size_t)((t << 6) + b) << 8) + tid] = d;
  }
  __syncthreads();
  int h = (half << 9) + tid;
  const unsigned short* ap = g.Aatt + ((size_t)b << 10) + h;
  float acc = 0;
  for (int s2 = 0; s2 < 256; s2++) acc += sc[s2] * b2f(ap[(size_t)s2 << 16]);
  g.summb[(b << 10) + h] = f2b(acc);
}

__device__ __forceinline__ void run_phase(const PK& g, int t, int ph, int bid, int tid,
                                          float (*red)[64][17], float* sc, float* ds) {
  int pr = t & 1;
  if (ph == 0) {
    const unsigned short* feed = (t == 0) ? g.feed0 : g.combb + ((size_t)(t - 1) << 16);
    gemm_phase(tid, bid << 4, g.embb + ((size_t)t << 15), Ed, feed, Hd, g.h0[pr], Hd,
               g.Wl0, Ed + 2 * Hd, 10, g.bsum0, g.c0, g.h0[1 - pr],
               nullptr, nullptr, 0, red);
  } else if (ph == 1) {
    gemm_phase(tid, bid << 4, g.h0[1 - pr], Hd, g.h1[pr], Hd, g.h1[pr], Hd,
               g.Wl1, 2 * Hd, 8, g.bsum1, g.c1, g.h1[1 - pr],
               nullptr, nullptr, 0, red);
  } else if (ph == 2) {
    if (bid < 128) {
      att_phase(tid, bid & 63, bid >> 6, t, g, g.h1[1 - pr], sc, ds);
    } else if (bid < 192) {
      gemm_phase(tid, (bid - 128) << 4, g.h1[1 - pr], Hd, g.h1[1 - pr], Hd,
                 g.h1[1 - pr], Hd, g.Wcb, 2 * Hd, 4, nullptr, nullptr, nullptr,
                 g.cpart, nullptr, 2, red);
    }
  } else {
    if (bid < 64) {
      gemm_phase(tid, bid << 4, g.summb, Hd, g.summb, Hd, g.summb, Hd,
                 g.Wcb + Hd, 2 * Hd, 4, nullptr, nullptr,
                 g.combb + ((size_t)t << 16), g.cpart, g.bc, 3, red);
    }
  }
}

__global__ __launch_bounds__(512) void k_recur(PK g) {
  __shared__ float red[8][64][17];
  __shared__ float sc[256];
  __shared__ float ds[256];
  cg::grid_group grid = cg::this_grid();
  int bid = blockIdx.x, tid = threadIdx.x;
  for (int t = 0; t < Td; t++) {
#pragma unroll 1
    for (int ph = 0; ph < 4; ph++) {
      run_phase(g, t, ph, bid, tid, red, sc, ds);
      grid.sync();
    }
  }
}

// non-cooperative fallback: one phase per launch
__global__ __launch_bounds__(512) void k_phase(PK g, int t, int ph) {
  __shared__ float red[8][64][17];
  __shared__ float sc[256];
  __shared__ float ds[256];
  run_phase(g, t, ph, blockIdx.x, threadIdx.x, red, sc, ds);
}

// ---------------- Phase A big GEMM: AMT = A @ MTT ----------------
__global__ __launch_bounds__(256) void k_gemm_amt(const unsigned short* __restrict__ A,
                                                  const unsigned short* __restrict__ Bw,
                                                  unsigned short* __restrict__ C) {
  __shared__ unsigned short As[128 * 40], Bs[128 * 40];
  int tid = threadIdx.x;
  int mb = blockIdx.x * 128, nb = blockIdx.y * 128;
  int wv = tid >> 6, lane = tid & 63, lq = lane >> 4, l16 = lane & 15;
  int mo = (wv & 1) * 64, no = (wv >> 1) * 64;
  int srow = tid >> 1, sh = (tid & 1) * 16;
  v4f acc[4][4];
#pragma unroll
  for (int i = 0; i < 4; i++)
#pragma unroll
    for (int j = 0; j < 4; j++) acc[i][j] = 0;
  const unsigned short* gA = A + (size_t)(mb + srow) * Hd + sh;
  const unsigned short* gB = Bw + (size_t)(nb + srow) * Hd + sh;
  for (int kc = 0; kc < Hd / 32; kc++) {
    v8s a0 = *(const v8s*)(gA + kc * 32);
    v8s a1 = *(const v8s*)(gA + kc * 32 + 8);
    v8s b0 = *(const v8s*)(gB + kc * 32);
    v8s b1 = *(const v8s*)(gB + kc * 32 + 8);
    __syncthreads();
    *(v8s*)&As[srow * 40 + sh] = a0;
    *(v8s*)&As[srow * 40 + sh + 8] = a1;
    *(v8s*)&Bs[srow * 40 + sh] = b0;
    *(v8s*)&Bs[srow * 40 + sh + 8] = b1;
    __syncthreads();
    v8s af[4], bf[4];
#pragma unroll
    for (int i = 0; i < 4; i++) af[i] = *(const v8s*)&As[(mo + i * 16 + l16) * 40 + lq * 8];
#pragma unroll
    for (int j = 0; j < 4; j++) bf[j] = *(const v8s*)&Bs[(no + j * 16 + l16) * 40 + lq * 8];
#pragma unroll
    for (int i = 0; i < 4; i++)
#pragma unroll
      for (int j = 0; j < 4; j++)
        acc[i][j] = __builtin_amdgcn_mfma_f32_16x16x32_bf16(af[i], bf[j], acc[i][j], 0, 0, 0);
  }
#pragma unroll
  for (int i = 0; i < 4; i++)
#pragma unroll
    for (int j = 0; j < 4; j++)
#pragma unroll
      for (int r = 0; r < 4; r++) {
        int row = mb + mo + i * 16 + lq * 4 + r;
        int col = nb + no + j * 16 + l16;
        C[(size_t)row * Hd + col] = f2b(acc[i][j][r]);
      }
}

// ---------------- Phase C ----------------
__global__ __launch_bounds__(256) void k_gemm_big(const unsigned short* __restrict__ A,
                                                  const unsigned short* __restrict__ Bw,
                                                  const float* __restrict__ bias,
                                                  float* __restrict__ C) {
  __shared__ unsigned short As[128 * 40], Bs[128 * 40];
  int tid = threadIdx.x;
  int mb = blockIdx.x * 128, nb = blockIdx.y * 128;
  int wv = tid >> 6, lane = tid & 63, lq = lane >> 4, l16 = lane & 15;
  int mo = (wv & 1) * 64, no = (wv >> 1) * 64;
  int srow = tid >> 1, sh = (tid & 1) * 16;
  v4f acc[4][4];
#pragma unroll
  for (int i = 0; i < 4; i++)
#pragma unroll
    for (int j = 0; j < 4; j++) acc[i][j] = 0;
  const unsigned short* gA = A + (size_t)(mb + srow) * Hd + sh;
  const unsigned short* gB = Bw + (size_t)(nb + srow) * Hd + sh;
  for (int kc = 0; kc < Hd / 32; kc++) {
    v8s a0 = *(const v8s*)(gA + kc * 32);
    v8s a1 = *(const v8s*)(gA + kc * 32 + 8);
    v8s b0 = *(const v8s*)(gB + kc * 32);
    v8s b1 = *(const v8s*)(gB + kc * 32 + 8);
    __syncthreads();
    *(v8s*)&As[srow * 40 + sh] = a0;
    *(v8s*)&As[srow * 40 + sh + 8] = a1;
    *(v8s*)&Bs[srow * 40 + sh] = b0;
    *(v8s*)&Bs[srow * 40 + sh + 8] = b1;
    __syncthreads();
    v8s af[4], bf[4];
#pragma unroll
    for (int i = 0; i < 4; i++) af[i] = *(const v8s*)&As[(mo + i * 16 + l16) * 40 + lq * 8];
#pragma unroll
    for (int j = 0; j < 4; j++) bf[j] = *(const v8s*)&Bs[(no + j * 16 + l16) * 40 + lq * 8];
#pragma unroll
    for (int i = 0; i < 4; i++)
#pragma unroll
      for (int j = 0; j < 4; j++)
        acc[i][j] = __builtin_amdgcn_mfma_f32_16x16x32_bf16(af[i], bf[j], acc[i][j], 0, 0, 0);
  }
#pragma unroll
  for (int i = 0; i < 4; i++)
#pragma unroll
    for (int j = 0; j < 4; j++)
#pragma unroll
      for (int r = 0; r < 4; r++) {
        int row = mb + mo + i * 16 + lq * 4 + r;
        int col = nb + no + j * 16 + l16;
        C[(size_t)row * Vd + col] = acc[i][j][r] + bias[col];
      }
}

// fused softmax + copy-scatter + log
#define VPT 32
__global__ __launch_bounds__(512) void k_epi(float* __restrict__ out,
                                             const float* __restrict__ distT,
                                             const int* __restrict__ atok) {
  __shared__ float bins[Vd];
  __shared__ float red[8];
  __shared__ float sh_e3;
  int row = blockIdx.x;  // t*64 + b
  int tid = threadIdx.x, w = tid >> 6, lane = tid & 63;
  float* p = out + (size_t)row * Vd;
  float ev[VPT];
  float mx = -1e30f;
#pragma unroll
  for (int j = 0; j < VPT; j++) {
    int col = j * 512 + tid;
    ev[j] = (col < Vd) ? p[col] : -1e30f;
    mx = fmaxf(mx, ev[j]);
  }
  for (int off = 32; off; off >>= 1) mx = fmaxf(mx, __shfl_xor(mx, off, 64));
  if (lane == 0) red[w] = mx;
  __syncthreads();
  float m = red[0];
#pragma unroll
  for (int i = 1; i < 8; i++) m = fmaxf(m, red[i]);
  __syncthreads();
  float sum = 0.f;
#pragma unroll
  for (int j = 0; j < VPT; j++) {
    int col = j * 512 + tid;
    float e = (col < Vd) ? expf(ev[j] - m) : 0.f;
    ev[j] = e;
    sum += e;
  }
  for (int off = 32; off; off >>= 1) sum += __shfl_xor(sum, off, 64);
  if (lane == 0) red[w] = sum;
  __syncthreads();
  float S = 0.f;
#pragma unroll
  for (int i = 0; i < 8; i++) S += red[i];
  if (tid == 3) sh_e3 = ev[0];  // e at col 3 (COPY)
  for (int i = tid; i < Vd; i += 512) bins[i] = 0.f;
  __syncthreads();
  if (tid < 256) {
    int s = tid, b = row & 63;
    float wv = distT[(size_t)row * Sd + s] * sh_e3;
    atomicAdd(&bins[atok[s * 64 + b]], wv);
  }
  __syncthreads();
  float lS = logf(S);
  float eS = 1e-7f * S;
#pragma unroll
  for (int j = 0; j < VPT; j++) {
    int col = j * 512 + tid;
    if (col < Vd)
      p[col] = (col == 3) ? logf(1e-7f) : (logf(ev[j] + bins[col] + eS) - lS);
  }
}

// ---------------- host launch ----------------

extern "C" void kernel_launch(void* const* d_in, const int* in_sizes, int n_in,
                              void* d_out, int out_size, void* d_ws, size_t ws_size,
                              hipStream_t stream) {
  (void)in_sizes; (void)out_size;
  if (n_in < 22) return;
  const int* ref_tokens   = (const int*)d_in[0];
  const int* att_tokens   = (const int*)d_in[1];
  const float* att_feat   = (const float*)d_in[2];
  const float* h0in       = (const float*)d_in[3];
  const float* c0in       = (const float*)d_in[4];
  const float* embed_w    = (const float*)d_in[5];
  const float* W_ih0      = (const float*)d_in[6];
  const float* W_hh0      = (const float*)d_in[7];
  const float* b_ih0      = (const float*)d_in[8];
  const float* b_hh0      = (const float*)d_in[9];
  const float* W_ih1      = (const float*)d_in[10];
  const float* W_hh1      = (const float*)d_in[11];
  const float* b_ih1      = (const float*)d_in[12];
  const float* b_hh1      = (const float*)d_in[13];
  const float* Wk         = (const float*)d_in[14];
  // d_in[15] = bk: dropped (softmax(axis=0)-invariant)
  const float* Wq         = (const float*)d_in[16];
  const float* bq         = (const float*)d_in[17];
  const float* Wc         = (const float*)d_in[18];
  const float* bc         = (const float*)d_in[19];
  const float* Wp         = (const float*)d_in[20];
  const float* bp         = (const float*)d_in[21];
  // d_in[22]/[23] = Wsp/bsp: dropped (softmax over singleton == 1)
  float* out = (float*)d_out;

  char* p = (char*)d_ws;
  auto alloc = [&](size_t bytes) -> char* {
    char* r = p; p += (bytes + 255) & ~(size_t)255; return r;
  };
  unsigned short* Wl0   = (unsigned short*)alloc((size_t)G4 * (Ed + 2 * Hd) * 2);
  unsigned short* Wl1   = (unsigned short*)alloc((size_t)G4 * 2 * Hd * 2);
  unsigned short* Wcb   = (unsigned short*)alloc((size_t)Hd * 2 * Hd * 2);
  unsigned short* Wpb   = (unsigned short*)alloc((size_t)Vd * Hd * 2);
  unsigned short* MTT   = (unsigned short*)alloc((size_t)Hd * Hd * 2);
  unsigned short* Aattb = (unsigned short*)alloc((size_t)Sd * Bd * Hd * 2);
  unsigned short* embb  = (unsigned short*)alloc((size_t)Td * Bd * Ed * 2);
  unsigned short* combb = (unsigned short*)alloc((size_t)Td * Bd * Hd * 2);
  float* distT          = (float*)alloc((size_t)Td * Bd * Sd * 4);
  float* sb0            = (float*)alloc((size_t)Sd * Bd * 4);
  float* biasq          = (float*)alloc((size_t)Hd * 4);
  float* bsum0          = (float*)alloc((size_t)G4 * 4);
  float* bsum1          = (float*)alloc((size_t)G4 * 4);
  unsigned short* h0a   = (unsigned short*)alloc((size_t)Bd * Hd * 2);
  unsigned short* h0b2  = (unsigned short*)alloc((size_t)Bd * Hd * 2);
  unsigned short* h1a   = (unsigned short*)alloc((size_t)Bd * Hd * 2);
  unsigned short* h1b2  = (unsigned short*)alloc((size_t)Bd * Hd * 2);
  float* c0f            = (float*)alloc((size_t)Bd * Hd * 4);
  float* c1f            = (float*)alloc((size_t)Bd * Hd * 4);
  unsigned short* feed0 = (unsigned short*)alloc((size_t)Bd * Hd * 2);
  unsigned short* summb = (unsigned short*)alloc((size_t)Bd * Hd * 2);
  float* cpart          = (float*)alloc((size_t)Bd * Hd * 4);
  if ((size_t)(p - (char*)d_ws) > ws_size) return;

  // AMT (S*B x H bf16, 33.5 MB) aliases the output buffer: only live during the
  // recurrence; Phase C's k_gemm_big overwrites out afterwards.
  unsigned short* AMTb = (unsigned short*)out;

  // ---- Phase A ----
  k_cvtgate<<<G4 * (Ed + 2 * Hd) / 256, 256, 0, stream>>>(W_ih0, W_hh0, Wl0, Ed + Hd, Ed + 2 * Hd);
  k_cvtgate<<<G4 * 2 * Hd / 256, 256, 0, stream>>>(W_ih1, W_hh1, Wl1, Hd, 2 * Hd);
  k_f2b<<<Hd * 2 * Hd / 256, 256, 0, stream>>>(Wc, Wcb, Hd * 2 * Hd);
  k_f2b<<<Vd * Hd / 256, 256, 0, stream>>>(Wp, Wpb, Vd * Hd);
  k_f2b<<<Sd * Bd * Hd / 256, 256, 0, stream>>>(att_feat, Aattb, Sd * Bd * Hd);
  k_embed<<<Td * Bd * Ed / 256, 256, 0, stream>>>(ref_tokens, embed_w, embb);
  k_mt<<<dim3(32, 32), 256, 0, stream>>>(Wk, Wq, MTT);
  k_biasq<<<4, 256, 0, stream>>>(bq, Wk, biasq);
  k_sb0<<<Sd * Bd / 4, 256, 0, stream>>>(Aattb, biasq, att_tokens, sb0);
  k_gemm_amt<<<dim3(Sd * Bd / 128, Hd / 128), 256, 0, stream>>>(Aattb, MTT, AMTb);
  k_bsum<<<16, 256, 0, stream>>>(b_ih0, b_hh0, bsum0);
  k_bsum<<<16, 256, 0, stream>>>(b_ih1, b_hh1, bsum1);
  k_init<<<Bd * Hd / 256, 256, 0, stream>>>(h0in, c0in, h0a, h1a, c0f, c1f, feed0);

  // ---- recurrence: one persistent cooperative kernel ----
  PK pk{};
  pk.embb = embb; pk.Wl0 = Wl0; pk.Wl1 = Wl1; pk.Wcb = Wcb;
  pk.AMT = AMTb; pk.Aatt = Aattb; pk.sb0 = sb0;
  pk.bsum0 = bsum0; pk.bsum1 = bsum1; pk.bc = bc;
  pk.c0 = c0f; pk.c1 = c1f;
  pk.h0[0] = h0a; pk.h0[1] = h0b2;
  pk.h1[0] = h1a; pk.h1[1] = h1b2;
  pk.feed0 = feed0; pk.combb = combb; pk.distT = distT;
  pk.summb = summb; pk.cpart = cpart;

  void* kargs[] = { (void*)&pk };
  hipError_t ce = hipLaunchCooperativeKernel((const void*)k_recur, dim3(256), dim3(512),
                                             kargs, 0, stream);
  if (ce != hipSuccess) {
    // fallback: per-phase launches (same device code)
    for (int t = 0; t < Td; t++) {
      k_phase<<<256, 512, 0, stream>>>(pk, t, 0);
      k_phase<<<256, 512, 0, stream>>>(pk, t, 1);
      k_phase<<<192, 512, 0, stream>>>(pk, t, 2);
      k_phase<<<64, 512, 0, stream>>>(pk, t, 3);
    }
  }

  // ---- Phase C ----
  k_gemm_big<<<dim3(32, 125), 256, 0, stream>>>(combb, Wpb, bp, out);
  k_epi<<<Td * Bd, 512, 0, stream>>>(out, distT, att_tokens);
}